// Round 9
// baseline (446.858 us; speedup 1.0000x reference)
//
#include <hip/hip_runtime.h>
#include <hip/hip_bf16.h>
#include <math.h>
#include <float.h>

#define B_Q   1024
#define N_M   50000
#define DIM   256
#define ATOMS 200
#define KSEL  8
#define NCHUNK 40
#define CHUNK  1280       // rows per chunk (16-aligned for fragment groups)
#define MT    128
#define NMT   10          // CHUNK/MT exactly
#define CPC   8           // candidates kept per (query, chunk)
#define NC    (NCHUNK * CPC)   // 320 candidates per query
#define T16   16          // finalize rescore set
#define WSTRIP 16         // transform rows per WAVE (v9: barrier-free strips)

typedef __attribute__((ext_vector_type(8))) short bf16x8;
typedef __attribute__((ext_vector_type(4))) float f32x4;

static __device__ inline unsigned short f2bf(float f) {
  __hip_bfloat16 h = __float2bfloat16(f);   // RNE
  return *reinterpret_cast<unsigned short*>(&h);
}

// RNE 3-way split (one-time W prep): x ~= s1+s2+s3, residual <= 2^-27 |x|
static __device__ inline void split3(float x, unsigned short& s1,
                                     unsigned short& s2, unsigned short& s3) {
  __hip_bfloat16 b1 = __float2bfloat16(x);
  float f1 = __bfloat162float(b1);
  float r1 = x - f1;
  __hip_bfloat16 b2 = __float2bfloat16(r1);
  float f2 = __bfloat162float(b2);
  __hip_bfloat16 b3 = __float2bfloat16(r1 - f2);
  s1 = *reinterpret_cast<unsigned short*>(&b1);
  s2 = *reinterpret_cast<unsigned short*>(&b2);
  s3 = *reinterpret_cast<unsigned short*>(&b3);
}

// Truncation 3-way split (hot path, 2 VALU/tier): residual <= 2^-24 |x|.
static __device__ inline void split3t(float x, unsigned short& s1,
                                      unsigned short& s2, unsigned short& s3) {
  const unsigned u = __float_as_uint(x);
  s1 = (unsigned short)(u >> 16);
  const float f1 = __uint_as_float(u & 0xffff0000u);
  const float r1 = x - f1;                       // exact
  const unsigned v = __float_as_uint(r1);
  s2 = (unsigned short)(v >> 16);
  const float f2 = __uint_as_float(v & 0xffff0000u);
  const float r2 = r1 - f2;                      // exact
  s3 = (unsigned short)(__float_as_uint(r2) >> 16);
}

// fp32 tanh via HW v_exp_f32 (~1ulp): rel err ~1.5e-7.
static __device__ inline float tanh32(float z) {
  float tz = fabsf(z) * 2.885390082f;           // 2|z|*log2(e)
  tz = fminf(tz, 120.f);
  const float E = __builtin_amdgcn_exp2f(tz);   // e^{2|z|}
  const float T = 1.f - 2.f / (E + 1.f);
  return (z >= 0.f) ? T : -T;
}

// ---------------------------------------------------------------------------
// W pre-split, v9: Wt planes in B-FRAGMENT-MAJOR layout (same convention as
// Hmb): for B element (n, k): off = ((n>>4)*8 + (k>>5))*512
//   + ((k>>3)&3)*128 + (n&15)*8 + (k&7).
// Makes transform's Wt loads single coalesced 1KB wave-loads (round-4/8 PMC:
// the old row-major pattern is 16-line TA-serialized).
// ---------------------------------------------------------------------------
__global__ __launch_bounds__(256) void wsplit_kernel(
    const float* __restrict__ W,
    unsigned short* __restrict__ Wt1, unsigned short* __restrict__ Wt2,
    unsigned short* __restrict__ Wt3)
{
  const int n = blockIdx.x;
  const int k = threadIdx.x;
  unsigned short s1, s2, s3;
  split3(W[(size_t)k * DIM + n], s1, s2, s3);
  const size_t off = ((size_t)(n >> 4) * 8 + (k >> 5)) * 512
                   + (size_t)(((k >> 3) & 3) * 128 + (n & 15) * 8 + (k & 7));
  Wt1[off] = s1;
  Wt2[off] = s2;
  Wt3[off] = s3;
}

// ---------------------------------------------------------------------------
// Transform v9: BARRIER-FREE per-wave strips. Round-8 post-mortem: v8's
// co-residency fix was neutral (109->113us) — the wall is latency chains
// (scattered row-major Wt loads + 4-barrier phase serialization), not
// capacity. v9 applies the two session-proven cures:
//   - Wt fragment-major (wsplit): B loads = coalesced 1KB wave-loads.
//   - each WAVE owns one 16-row strip x all 256 cols, NO LDS, NO barriers:
//     per kstep: lane loads its own 8 fp32 of X (A-frag layout, 32B
//     contiguous), splits in-register, then 16 tiles x {3 B loads + 6 MFMA}.
//     acc = 16 x f32x4 = 64 VGPR.
//   - epilogue wave-local: row-norm = sum over 16 tiles + 4-step shfl_xor
//     over lx; ysq = nsq*sc^2 (second reduce eliminated algebraically).
// D layout per tile: col=lane&15 (n within tile), row=quad*4+reg (m).
// Hb stays FRAGMENT-MAJOR, same writer formula as v8 (score reader
// unchanged, verified).
// ---------------------------------------------------------------------------
__global__ __launch_bounds__(256) void transform_kernel(
    const float* __restrict__ X, int nrows,
    const unsigned short* __restrict__ Wt1, const unsigned short* __restrict__ Wt2,
    const unsigned short* __restrict__ Wt3, const float* __restrict__ bvec,
    float* __restrict__ H, unsigned short* __restrict__ Hb,
    float2* __restrict__ aux)
{
  const int t    = threadIdx.x;
  const int lane = t & 63;
  const int wave = t >> 6;          // 0..3
  const int lx   = lane & 15;
  const int quad = lane >> 4;
  const int row0w = (blockIdx.x * 4 + wave) * WSTRIP;   // this wave's strip

  int gr = row0w + lx; if (gr >= nrows) gr = nrows - 1;  // A row (clamped; stores guarded)
  const float* Xr = X + (size_t)gr * DIM + quad * 8;

  f32x4 acc[16];
#pragma unroll
  for (int nt = 0; nt < 16; ++nt) { acc[nt][0] = 0.f; acc[nt][1] = 0.f;
                                    acc[nt][2] = 0.f; acc[nt][3] = 0.f; }

  for (int ks = 0; ks < 8; ++ks) {
    // A: lane's 8 consecutive fp32 (row gr, cols ks*32+quad*8..+8) -> 3 tiers
    const float4 xa = *(const float4*)(Xr + ks * 32);
    const float4 xb = *(const float4*)(Xr + ks * 32 + 4);
    bf16x8 a1, a2, a3;
    {
      const float xv[8] = {xa.x, xa.y, xa.z, xa.w, xb.x, xb.y, xb.z, xb.w};
#pragma unroll
      for (int i = 0; i < 8; ++i) {
        unsigned short s1, s2, s3;
        split3t(xv[i], s1, s2, s3);
        a1[i] = (short)s1; a2[i] = (short)s2; a3[i] = (short)s3;
      }
    }
    const size_t bko = (size_t)ks * 512 + (size_t)lane * 8;
#pragma unroll
    for (int nt = 0; nt < 16; ++nt) {
      const size_t bo = (size_t)nt * 4096 + bko;    // frag (g=nt, ks) block
      const bf16x8 b1 = *(const bf16x8*)(Wt1 + bo);
      const bf16x8 b2 = *(const bf16x8*)(Wt2 + bo);
      const bf16x8 b3 = *(const bf16x8*)(Wt3 + bo);
      acc[nt] = __builtin_amdgcn_mfma_f32_16x16x32_bf16(a1, b1, acc[nt], 0, 0, 0);
      acc[nt] = __builtin_amdgcn_mfma_f32_16x16x32_bf16(a1, b2, acc[nt], 0, 0, 0);
      acc[nt] = __builtin_amdgcn_mfma_f32_16x16x32_bf16(a2, b1, acc[nt], 0, 0, 0);
      acc[nt] = __builtin_amdgcn_mfma_f32_16x16x32_bf16(a1, b3, acc[nt], 0, 0, 0);
      acc[nt] = __builtin_amdgcn_mfma_f32_16x16x32_bf16(a2, b2, acc[nt], 0, 0, 0);
      acc[nt] = __builtin_amdgcn_mfma_f32_16x16x32_bf16(a3, b1, acc[nt], 0, 0, 0);
    }
  }

  // bias + tanh, in place (lane holds rows quad*4+r, col nt*16+lx)
#pragma unroll
  for (int nt = 0; nt < 16; ++nt) {
    const float bb = bvec[nt * 16 + lx];
#pragma unroll
    for (int r = 0; r < 4; ++r)
      acc[nt][r] = tanh32(acc[nt][r] + bb);
  }

  // row norms: sum over 16 tiles locally, then over the 16 lx lanes (in-quad)
  float nsq[4] = {0.f, 0.f, 0.f, 0.f};
#pragma unroll
  for (int nt = 0; nt < 16; ++nt)
#pragma unroll
    for (int r = 0; r < 4; ++r) nsq[r] += acc[nt][r] * acc[nt][r];
#pragma unroll
  for (int off = 1; off < 16; off <<= 1)
#pragma unroll
    for (int r = 0; r < 4; ++r) nsq[r] += __shfl_xor(nsq[r], off);

  float sc[4], ys[4];
#pragma unroll
  for (int r = 0; r < 4; ++r) {
    const float nrm = sqrtf(nsq[r]);
    sc[r] = (nrm > 0.95f) ? (0.95f / nrm) : 1.f;
    ys[r] = nsq[r] * sc[r] * sc[r];
  }

  // aux: lx==0 lane of each quad owns rows quad*4+0..3
  if (lx == 0) {
#pragma unroll
    for (int r = 0; r < 4; ++r) {
      const int grow = row0w + quad * 4 + r;
      if (grow < nrows) aux[grow] = make_float2(ys[r], 1.f / (1.f - ys[r]));
    }
  }

  // stores: H fp32 (row-major) + Hb bf16 (FRAGMENT-MAJOR), guarded rows
  const int g = row0w >> 4;
#pragma unroll
  for (int nt = 0; nt < 16; ++nt) {
    const int col = nt * 16 + lx;
    const size_t hbbase = ((size_t)g * 8 + (col >> 5)) * 512
                        + (size_t)(((col >> 3) & 3) * 128 + (col & 7));
#pragma unroll
    for (int r = 0; r < 4; ++r) {
      const int grow = row0w + quad * 4 + r;
      if (grow < nrows) {
        const float u = acc[nt][r] * sc[r];
        H[(size_t)grow * DIM + col] = u;
        Hb[hbbase + (size_t)(quad * 4 + r) * 8] = f2bf(u);
      }
    }
  }
}

// ---------------------------------------------------------------------------
// Score (MFMA), v7 (unchanged): coalesced frag-major pipeline + u32 packed
// keys + 5-op min/max sorted insert. See round-6/7 notes: coalescing took
// 154->110us; u32 keys cut the VALU insert cost (score now <108us).
// key = (fp32 score bits & ~31) | (mt*2+ms); decode at extraction:
// gi = mbase + wave*32 + lx + mt*128 + ms*16. fp64 rescore fixes order.
// ---------------------------------------------------------------------------
__global__ __launch_bounds__(256) void score_kernel(
    const unsigned short* __restrict__ Hqb, const unsigned short* __restrict__ Hmb,
    const float2* __restrict__ auxq, const float2* __restrict__ auxm,
    float* __restrict__ cand_s, int* __restrict__ cand_i)
{
  __shared__ __align__(16) unsigned short Afs[16 * 64 * 8]; // 16 KB, frag-order
  __shared__ unsigned long long wtop[4][32][CPC];           // 8 KB

  const int t    = threadIdx.x;
  const int lane = t & 63;
  const int wave = t >> 6;
  const int q0   = blockIdx.y * 32;
  const int c    = blockIdx.x;
  const int mbase = c * CHUNK;
  const int lx   = lane & 15;
  const int quad = lane >> 4;

  // stage A fragments into LDS (slot = ks*2+qs; frag-major source, coalesced)
#pragma unroll
  for (int i = 0; i < 4; ++i) {
    const int sl = wave * 4 + i;
    const int ks = sl >> 1, qs = sl & 1;
    const bf16x8 a = *(const bf16x8*)(Hqb + ((size_t)((q0 >> 4) + qs) * 8 + ks) * 512 + (size_t)lane * 8);
    *(bf16x8*)(Afs + ((size_t)sl * 64 + lane) * 8) = a;
  }
  // per-row query norms (row = qs*4+r; rows 0-3 -> qs=0, rows 4-7 -> qs=1)
  const float xq0 = auxq[q0 +      quad * 4 + 0].x;
  const float xq1 = auxq[q0 +      quad * 4 + 1].x;
  const float xq2 = auxq[q0 +      quad * 4 + 2].x;
  const float xq3 = auxq[q0 +      quad * 4 + 3].x;
  const float xq4 = auxq[q0 + 16 + quad * 4 + 0].x;
  const float xq5 = auxq[q0 + 16 + quad * 4 + 1].x;
  const float xq6 = auxq[q0 + 16 + quad * 4 + 2].x;
  const float xq7 = auxq[q0 + 16 + quad * 4 + 3].x;
  __syncthreads();          // the ONLY pre-merge barrier

  // 24 named packed u32 top-3 keys (sorted ascending: a <= b <= c)
  unsigned t0a=0xFFFFFFFFu,t0b=0xFFFFFFFFu,t0c=0xFFFFFFFFu;
  unsigned t1a=0xFFFFFFFFu,t1b=0xFFFFFFFFu,t1c=0xFFFFFFFFu;
  unsigned t2a=0xFFFFFFFFu,t2b=0xFFFFFFFFu,t2c=0xFFFFFFFFu;
  unsigned t3a=0xFFFFFFFFu,t3b=0xFFFFFFFFu,t3c=0xFFFFFFFFu;
  unsigned t4a=0xFFFFFFFFu,t4b=0xFFFFFFFFu,t4c=0xFFFFFFFFu;
  unsigned t5a=0xFFFFFFFFu,t5b=0xFFFFFFFFu,t5c=0xFFFFFFFFu;
  unsigned t6a=0xFFFFFFFFu,t6b=0xFFFFFFFFu,t6c=0xFFFFFFFFu;
  unsigned t7a=0xFFFFFFFFu,t7b=0xFFFFFFFFu,t7c=0xFFFFFFFFu;

  const int colw = wave * 32 + lx;       // within-128-tile column, ms=0

  // fragment-major B pointer: wave's group pair g0 = (mbase>>4) + wave*2
  // frag (g, ks) block = 512 elems; group stride = 8*512 = 4096 elems.
  const unsigned short* Bp = Hmb + (size_t)((mbase >> 4) + wave * 2) * 4096 + (size_t)lane * 8;
#define LD(OFS) (*(const bf16x8*)(Bp + (OFS)))

// one MFMA k-step: A slots (KS*2+0 / KS*2+1) x named B frags
#define KSTEP(KS, BA, BB) do {                                                        \
    const bf16x8 a0_ = *(const bf16x8*)(Afs + (((KS) * 2 + 0) * 64 + lane) * 8);      \
    const bf16x8 a1_ = *(const bf16x8*)(Afs + (((KS) * 2 + 1) * 64 + lane) * 8);      \
    acc00 = __builtin_amdgcn_mfma_f32_16x16x32_bf16(a0_, BA, acc00, 0, 0, 0);         \
    acc01 = __builtin_amdgcn_mfma_f32_16x16x32_bf16(a0_, BB, acc01, 0, 0, 0);         \
    acc10 = __builtin_amdgcn_mfma_f32_16x16x32_bf16(a1_, BA, acc10, 0, 0, 0);         \
    acc11 = __builtin_amdgcn_mfma_f32_16x16x32_bf16(a1_, BB, acc11, 0, 0, 0);         \
  } while (0)

// u32-key score + 5-op sorted-insert (keep 3 smallest), unconditional
#define SCOREU(ACC, R, YM, RO, CODE, XQ, T0, T1, T2) do {                             \
    const float sv_ = fmaxf(fmaf(-2.f, (ACC)[R], (XQ) + (YM)), 0.f) * (RO);           \
    const unsigned k_ = (__float_as_uint(sv_) & 0xFFFFFFE0u) | (unsigned)(CODE);      \
    const unsigned a_ = min(T0, k_);                                                  \
    const unsigned x_ = max(T0, k_);                                                  \
    const unsigned b_ = min(T1, x_);                                                  \
    const unsigned y_ = max(T1, x_);                                                  \
    const unsigned c_ = min(T2, y_);                                                  \
    T0 = a_; T1 = b_; T2 = c_;                                                        \
  } while (0)

// masked variant (tail chunk only): invalid -> 0xFFFFFFFF sentinel
#define SCOREM(ACC, R, YM, RO, OK, CODE, XQ, T0, T1, T2) do {                         \
    const float sv_ = fmaxf(fmaf(-2.f, (ACC)[R], (XQ) + (YM)), 0.f) * (RO);           \
    const unsigned kr_ = (__float_as_uint(sv_) & 0xFFFFFFE0u) | (unsigned)(CODE);     \
    const unsigned k_ = (OK) ? kr_ : 0xFFFFFFFFu;                                     \
    const unsigned a_ = min(T0, k_);                                                  \
    const unsigned x_ = max(T0, k_);                                                  \
    const unsigned b_ = min(T1, x_);                                                  \
    const unsigned y_ = max(T1, x_);                                                  \
    const unsigned c_ = min(T2, y_);                                                  \
    T0 = a_; T1 = b_; T2 = c_;                                                        \
  } while (0)

#define SCORE16U(C0, C1) do {                                                         \
    const float ym0 = aux0.x, ro0 = aux0.y;                                           \
    const float ym1 = aux1.x, ro1 = aux1.y;                                           \
    SCOREU(acc00, 0, ym0, ro0, C0, xq0, t0a, t0b, t0c);                               \
    SCOREU(acc00, 1, ym0, ro0, C0, xq1, t1a, t1b, t1c);                               \
    SCOREU(acc00, 2, ym0, ro0, C0, xq2, t2a, t2b, t2c);                               \
    SCOREU(acc00, 3, ym0, ro0, C0, xq3, t3a, t3b, t3c);                               \
    SCOREU(acc01, 0, ym1, ro1, C1, xq0, t0a, t0b, t0c);                               \
    SCOREU(acc01, 1, ym1, ro1, C1, xq1, t1a, t1b, t1c);                               \
    SCOREU(acc01, 2, ym1, ro1, C1, xq2, t2a, t2b, t2c);                               \
    SCOREU(acc01, 3, ym1, ro1, C1, xq3, t3a, t3b, t3c);                               \
    SCOREU(acc10, 0, ym0, ro0, C0, xq4, t4a, t4b, t4c);                               \
    SCOREU(acc10, 1, ym0, ro0, C0, xq5, t5a, t5b, t5c);                               \
    SCOREU(acc10, 2, ym0, ro0, C0, xq6, t6a, t6b, t6c);                               \
    SCOREU(acc10, 3, ym0, ro0, C0, xq7, t7a, t7b, t7c);                               \
    SCOREU(acc11, 0, ym1, ro1, C1, xq4, t4a, t4b, t4c);                               \
    SCOREU(acc11, 1, ym1, ro1, C1, xq5, t5a, t5b, t5c);                               \
    SCOREU(acc11, 2, ym1, ro1, C1, xq6, t6a, t6b, t6c);                               \
    SCOREU(acc11, 3, ym1, ro1, C1, xq7, t7a, t7b, t7c);                               \
  } while (0)

#define SCORE16M(OK0, OK1, C0, C1) do {                                               \
    const float ym0 = aux0.x, ro0 = aux0.y;                                           \
    const float ym1 = aux1.x, ro1 = aux1.y;                                           \
    SCOREM(acc00, 0, ym0, ro0, OK0, C0, xq0, t0a, t0b, t0c);                          \
    SCOREM(acc00, 1, ym0, ro0, OK0, C0, xq1, t1a, t1b, t1c);                          \
    SCOREM(acc00, 2, ym0, ro0, OK0, C0, xq2, t2a, t2b, t2c);                          \
    SCOREM(acc00, 3, ym0, ro0, OK0, C0, xq3, t3a, t3b, t3c);                          \
    SCOREM(acc01, 0, ym1, ro1, OK1, C1, xq0, t0a, t0b, t0c);                          \
    SCOREM(acc01, 1, ym1, ro1, OK1, C1, xq1, t1a, t1b, t1c);                          \
    SCOREM(acc01, 2, ym1, ro1, OK1, C1, xq2, t2a, t2b, t2c);                          \
    SCOREM(acc01, 3, ym1, ro1, OK1, C1, xq3, t3a, t3b, t3c);                          \
    SCOREM(acc10, 0, ym0, ro0, OK0, C0, xq4, t4a, t4b, t4c);                          \
    SCOREM(acc10, 1, ym0, ro0, OK0, C0, xq5, t5a, t5b, t5c);                          \
    SCOREM(acc10, 2, ym0, ro0, OK0, C0, xq6, t6a, t6b, t6c);                          \
    SCOREM(acc10, 3, ym0, ro0, OK0, C0, xq7, t7a, t7b, t7c);                          \
    SCOREM(acc11, 0, ym1, ro1, OK1, C1, xq4, t4a, t4b, t4c);                          \
    SCOREM(acc11, 1, ym1, ro1, OK1, C1, xq5, t5a, t5b, t5c);                          \
    SCOREM(acc11, 2, ym1, ro1, OK1, C1, xq6, t6a, t6b, t6c);                          \
    SCOREM(acc11, 3, ym1, ro1, OK1, C1, xq7, t7a, t7b, t7c);                          \
  } while (0)

  if (c != NCHUNK - 1) {
    // ---- chunks 0..38: 10 full unmasked mtiles, half-tile pipeline ----
    int midx = mbase + colw;   // only for aux addressing
    // preload X = k-half0 of mtile 0 (ks0..3 of both 16-row groups)
    bf16x8 xA0 = LD(0),    xA1 = LD(512),  xA2 = LD(1024), xA3 = LD(1536);
    bf16x8 xB0 = LD(4096), xB1 = LD(4608), xB2 = LD(5120), xB3 = LD(5632);

    for (int mt = 0; mt < NMT - 1; ++mt) {   // mt 0..8: branch-free body
      // issue Y = k-half1 of current mtile
      bf16x8 yA0 = LD(2048), yA1 = LD(2560), yA2 = LD(3072), yA3 = LD(3584);
      bf16x8 yB0 = LD(6144), yB1 = LD(6656), yB2 = LD(7168), yB3 = LD(7680);
      const float2 aux0 = auxm[midx];
      const float2 aux1 = auxm[midx + 16];

      f32x4 acc00 = {0.f, 0.f, 0.f, 0.f};
      f32x4 acc01 = {0.f, 0.f, 0.f, 0.f};
      f32x4 acc10 = {0.f, 0.f, 0.f, 0.f};
      f32x4 acc11 = {0.f, 0.f, 0.f, 0.f};

      KSTEP(0, xA0, xB0);
      KSTEP(1, xA1, xB1);
      KSTEP(2, xA2, xB2);
      KSTEP(3, xA3, xB3);

      // advance, issue X of NEXT mtile (in flight across inserts)
      Bp += 8 * 4096;
      xA0 = LD(0);    xA1 = LD(512);  xA2 = LD(1024); xA3 = LD(1536);
      xB0 = LD(4096); xB1 = LD(4608); xB2 = LD(5120); xB3 = LD(5632);

      KSTEP(4, yA0, yB0);
      KSTEP(5, yA1, yB1);
      KSTEP(6, yA2, yB2);
      KSTEP(7, yA3, yB3);

      SCORE16U(mt * 2, mt * 2 + 1);
      midx += MT;
    }

    { // final mtile mt=9 (X preloaded, no further prefetch), unmasked
      bf16x8 yA0 = LD(2048), yA1 = LD(2560), yA2 = LD(3072), yA3 = LD(3584);
      bf16x8 yB0 = LD(6144), yB1 = LD(6656), yB2 = LD(7168), yB3 = LD(7680);
      const float2 aux0 = auxm[midx];
      const float2 aux1 = auxm[midx + 16];

      f32x4 acc00 = {0.f, 0.f, 0.f, 0.f};
      f32x4 acc01 = {0.f, 0.f, 0.f, 0.f};
      f32x4 acc10 = {0.f, 0.f, 0.f, 0.f};
      f32x4 acc11 = {0.f, 0.f, 0.f, 0.f};

      KSTEP(0, xA0, xB0);
      KSTEP(1, xA1, xB1);
      KSTEP(2, xA2, xB2);
      KSTEP(3, xA3, xB3);
      KSTEP(4, yA0, yB0);
      KSTEP(5, yA1, yB1);
      KSTEP(6, yA2, yB2);
      KSTEP(7, yA3, yB3);

      SCORE16U((NMT - 1) * 2, (NMT - 1) * 2 + 1);
    }
  } else {
    // ---- tail chunk 39: rows 49920..49999 valid (80) -> 1 masked mtile ----
    // Reads stay within the padded 50048-row fragment region; junk cols
    // (incl. possible NaN) cndmask'd to sentinel BEFORE insert.
    const int vrem = N_M - mbase;               // 80
    const bool ok0 = colw < vrem;
    const bool ok1 = colw + 16 < vrem;
    const int midx = mbase + colw;

    bf16x8 xA0 = LD(0),    xA1 = LD(512),  xA2 = LD(1024), xA3 = LD(1536);
    bf16x8 xB0 = LD(4096), xB1 = LD(4608), xB2 = LD(5120), xB3 = LD(5632);
    bf16x8 yA0 = LD(2048), yA1 = LD(2560), yA2 = LD(3072), yA3 = LD(3584);
    bf16x8 yB0 = LD(6144), yB1 = LD(6656), yB2 = LD(7168), yB3 = LD(7680);
    const float2 aux0 = auxm[midx];
    const float2 aux1 = auxm[midx + 16];

    f32x4 acc00 = {0.f, 0.f, 0.f, 0.f};
    f32x4 acc01 = {0.f, 0.f, 0.f, 0.f};
    f32x4 acc10 = {0.f, 0.f, 0.f, 0.f};
    f32x4 acc11 = {0.f, 0.f, 0.f, 0.f};

    KSTEP(0, xA0, xB0);
    KSTEP(1, xA1, xB1);
    KSTEP(2, xA2, xB2);
    KSTEP(3, xA3, xB3);
    KSTEP(4, yA0, yB0);
    KSTEP(5, yA1, yB1);
    KSTEP(6, yA2, yB2);
    KSTEP(7, yA3, yB3);

    SCORE16M(ok0, ok1, 0, 1);
  }

#undef LD
#undef KSTEP
#undef SCOREU
#undef SCOREM
#undef SCORE16U
#undef SCORE16M

  // key -> u64 (key<<32 | global index): restores unique keys for the
  // equality-pop merge. decode: mt=(k>>1)&15, ms=k&1.
#define K2E(K) ( (((unsigned long long)(K)) << 32) |                                  \
    (unsigned)(mbase + wave * 32 + lx + (((K) & 30u) >> 1) * 128 + ((K) & 1u) * 16) )

  // per-wave extraction: per query-row, 16 lanes x top-3 -> wave top-8.
  // (quads handle 4 query-rows in parallel; shfl offsets 1..8 stay in-quad)
#define EXTRACT_ROW(WIDX, T0, T1, T2) do {                                            \
    unsigned long long p0 = K2E(T0), p1 = K2E(T1), p2 = K2E(T2);                      \
    for (int rd = 0; rd < CPC; ++rd) {                                                \
      unsigned long long lm = (p0 < p1) ? p0 : p1;                                    \
      lm = (p2 < lm) ? p2 : lm;                                                       \
      unsigned long long gm = lm;                                                     \
      for (int off = 1; off < 16; off <<= 1) {                                        \
        const unsigned long long o = __shfl_xor(gm, off);                             \
        gm = (o < gm) ? o : gm;                                                       \
      }                                                                               \
      if      (p0 == gm) p0 = ~0ULL;                                                  \
      else if (p1 == gm) p1 = ~0ULL;                                                  \
      else if (p2 == gm) p2 = ~0ULL;                                                  \
      if (lx == 0) wtop[wave][WIDX][rd] = gm;                                         \
    }                                                                                 \
  } while (0)

  EXTRACT_ROW(quad * 4 + 0,      t0a, t0b, t0c);
  EXTRACT_ROW(quad * 4 + 1,      t1a, t1b, t1c);
  EXTRACT_ROW(quad * 4 + 2,      t2a, t2b, t2c);
  EXTRACT_ROW(quad * 4 + 3,      t3a, t3b, t3c);
  EXTRACT_ROW(16 + quad * 4 + 0, t4a, t4b, t4c);
  EXTRACT_ROW(16 + quad * 4 + 1, t5a, t5b, t5c);
  EXTRACT_ROW(16 + quad * 4 + 2, t6a, t6b, t6c);
  EXTRACT_ROW(16 + quad * 4 + 3, t7a, t7b, t7c);
#undef EXTRACT_ROW
#undef K2E
  __syncthreads();

  // cross-wave merge: 8 threads per query, 4 waves x 8 -> top-8 -> cand
  {
    const int qr = t >> 3;        // 0..31
    const int sp = t & 7;
    unsigned long long v0 = wtop[0][qr][sp];
    unsigned long long v1 = wtop[1][qr][sp];
    unsigned long long v2 = wtop[2][qr][sp];
    unsigned long long v3 = wtop[3][qr][sp];
    const size_t cbase = ((size_t)(q0 + qr) * NCHUNK + c) * CPC;
    for (int rd = 0; rd < CPC; ++rd) {
      unsigned long long lm = (v0 < v1) ? v0 : v1;
      const unsigned long long l2 = (v2 < v3) ? v2 : v3;
      lm = (l2 < lm) ? l2 : lm;
      unsigned long long gm = lm;
#pragma unroll
      for (int off = 1; off < 8; off <<= 1) {
        const unsigned long long o = __shfl_xor(gm, off);
        gm = (o < gm) ? o : gm;
      }
      if      (v0 == gm) v0 = ~0ULL;
      else if (v1 == gm) v1 = ~0ULL;
      else if (v2 == gm) v2 = ~0ULL;
      else if (v3 == gm) v3 = ~0ULL;
      if (sp == 0) {
        cand_s[cbase + rd] = __uint_as_float((unsigned int)(gm >> 32));
        cand_i[cbase + rd] = (int)(unsigned int)(gm & 0xffffffffu);
      }
    }
  }
}

// ---------------------------------------------------------------------------
// Finalize: per query, 256 threads (4 waves): parallel candidate merge
// 320 -> 4x16 -> top-16 (fp32 score, idx tie-break), fp64 rescore (4 cands
// per wave) -> exact top-8 order, softmax, parallel mask gather.
// ---------------------------------------------------------------------------
__global__ __launch_bounds__(256) void finalize_kernel(
    const float* __restrict__ Hq, const float* __restrict__ Hm,
    const float* __restrict__ masks,
    const float* __restrict__ cand_s, const int* __restrict__ cand_i,
    float* __restrict__ outW, float* __restrict__ outH)
{
  const int q    = blockIdx.x;
  const int t    = threadIdx.x;
  const int lane = t & 63;
  const int wave = t >> 6;

  __shared__ unsigned long long wtop[4][T16];
  __shared__ int    selIdx[T16];
  __shared__ double dArr[T16];
  __shared__ int    fin_i[KSEL];
  __shared__ double fin_d[KSEL];
  __shared__ double ew[KSEL];

  // phase 1: each wave takes 80 candidates -> its top-16 (indices unique)
  {
    const size_t base = (size_t)q * NC + (size_t)wave * (NC / 4);
    unsigned long long pk[2];
#pragma unroll
    for (int s = 0; s < 2; ++s) {
      const int c = lane + 64 * s;
      pk[s] = (c < NC / 4)
        ? ((((unsigned long long)__float_as_uint(cand_s[base + c])) << 32) | (unsigned int)cand_i[base + c])
        : ~0ULL;
    }
    for (int r = 0; r < T16; ++r) {
      unsigned long long lm = (pk[0] < pk[1]) ? pk[0] : pk[1];
      unsigned long long gm = lm;
#pragma unroll
      for (int off = 1; off < 64; off <<= 1) {
        unsigned long long o = __shfl_xor(gm, off);
        gm = (o < gm) ? o : gm;
      }
      bool done = false;
#pragma unroll
      for (int s = 0; s < 2; ++s) if (!done && pk[s] == gm) { pk[s] = ~0ULL; done = true; }
      if (lane == 0) wtop[wave][r] = gm;
    }
  }
  __syncthreads();

  // phase 2: wave 0 merges 64 -> global top-16
  if (wave == 0) {
    unsigned long long v = wtop[lane >> 4][lane & 15];
    for (int r = 0; r < T16; ++r) {
      unsigned long long gm = v;
#pragma unroll
      for (int off = 1; off < 64; off <<= 1) {
        unsigned long long o = __shfl_xor(gm, off);
        gm = (o < gm) ? o : gm;
      }
      if (v == gm) v = ~0ULL;
      if (lane == 0) selIdx[r] = (int)(unsigned int)(gm & 0xffffffffULL);
    }
  }
  __syncthreads();

  // phase 3: fp64 rescore, 4 candidates per wave
  const float4 q4 = *(const float4*)(Hq + (size_t)q * DIM + 4 * lane);
  double xp_ = (double)q4.x * q4.x + (double)q4.y * q4.y + (double)q4.z * q4.z + (double)q4.w * q4.w;
#pragma unroll
  for (int off = 1; off < 64; off <<= 1) xp_ += __shfl_xor(xp_, off);
  const double xsq = xp_;

  for (int r = wave; r < T16; r += 4) {
    const int cidx = selIdx[r];
    const float4 m4 = *(const float4*)(Hm + (size_t)cidx * DIM + 4 * lane);
    double dp = (double)q4.x * m4.x + (double)q4.y * m4.y + (double)q4.z * m4.z + (double)q4.w * m4.w;
    double yp = (double)m4.x * m4.x + (double)m4.y * m4.y + (double)m4.z * m4.z + (double)m4.w * m4.w;
#pragma unroll
    for (int off = 1; off < 64; off <<= 1) { dp += __shfl_xor(dp, off); yp += __shfl_xor(yp, off); }
    if (lane == 0) {
      double diff = xsq + yp - 2.0 * dp; if (diff < 0.0) diff = 0.0;
      double den = (1.0 - xsq) * (1.0 - yp);
      double arg = 1.0 + 2.0 * diff / (den + 1e-8);
      const double lo = 1.0 + 1e-6;
      if (arg < lo) arg = lo;
      dArr[r] = log(arg + sqrt(arg * arg - 1.0));   // arccosh
    }
  }
  __syncthreads();

  // phase 4: exact rank (dist, idx) -> top-8, softmax
  if (t < T16) {
    const double dj = dArr[t]; const int ij = selIdx[t];
    int rank = 0;
#pragma unroll
    for (int i = 0; i < T16; ++i)
      rank += (dArr[i] < dj || (dArr[i] == dj && selIdx[i] < ij)) ? 1 : 0;
    if (rank < KSEL) { fin_d[rank] = dj; fin_i[rank] = ij; }
  }
  __syncthreads();
  if (t < KSEL) ew[t] = exp(fin_d[0] - fin_d[t]);
  __syncthreads();
  if (t < KSEL) {
    double ssum = 0.0;
#pragma unroll
    for (int i = 0; i < KSEL; ++i) ssum += ew[i];
    outW[(size_t)q * KSEL + t] = (float)(ew[t] / ssum);
  }

  // phase 5: mask gather, 32 threads per output row
  const int g  = t >> 5;
  const int l0 = t & 31;
  const int row = fin_i[g];
  for (int l = l0; l < ATOMS; l += 32)
    outH[((size_t)q * KSEL + g) * ATOMS + l] = masks[(size_t)row * ATOMS + l];
}

// ---------------------------------------------------------------------------
extern "C" void kernel_launch(void* const* d_in, const int* in_sizes, int n_in,
                              void* d_out, int out_size, void* d_ws, size_t ws_size,
                              hipStream_t stream) {
  const float* Q     = (const float*)d_in[0];   // [1024,256]
  const float* M     = (const float*)d_in[1];   // [50000,256]
  const float* masks = (const float*)d_in[2];   // [50000,200]
  const float* W     = (const float*)d_in[3];   // [256,256]
  const float* bv    = (const float*)d_in[4];   // [256]
  // d_in[5] = k (always 8, hard-coded)

  char* w = (char*)d_ws;
  float*          Hq   = (float*)(w);                       //  1,048,576 B
  float*          Hm   = (float*)(w + 1048576);             // 51,200,000 B
  unsigned short* Hqb  = (unsigned short*)(w + 52248576);   //    524,288 B (frag-major, 64 groups)
  unsigned short* Hmb  = (unsigned short*)(w + 52772864);   // 25,624,576 B (frag-major, 3128 groups = 50048 rows)
  float2*         auxq = (float2*)(w + 78397440);           //      8,192 B
  float2*         auxm = (float2*)(w + 78405632);           //    400,384 B (padded to 50048)
  float*          cs   = (float*)(w + 78806016);            //  1,310,720 B
  int*            cix  = (int*)(w + 80116736);              //  1,310,720 B -> 81,427,456 total

  // Wt bf16 planes alias the cand_s region (dead until score_kernel writes it)
  unsigned short* Wt1 = (unsigned short*)(w + 78806016);    // 3 x 131,072 B (frag-major)
  unsigned short* Wt2 = Wt1 + DIM * DIM;
  unsigned short* Wt3 = Wt2 + DIM * DIM;

  wsplit_kernel<<<DIM, DIM, 0, stream>>>(W, Wt1, Wt2, Wt3);
  transform_kernel<<<(B_Q + 4 * WSTRIP - 1) / (4 * WSTRIP), 256, 0, stream>>>(Q, B_Q, Wt1, Wt2, Wt3, bv, Hq, Hqb, auxq);
  transform_kernel<<<(N_M + 4 * WSTRIP - 1) / (4 * WSTRIP), 256, 0, stream>>>(M, N_M, Wt1, Wt2, Wt3, bv, Hm, Hmb, auxm);
  score_kernel<<<dim3(NCHUNK, B_Q / 32), 256, 0, stream>>>(Hqb, Hmb, auxq, auxm, cs, cix);
  finalize_kernel<<<B_Q, 256, 0, stream>>>(Hq, Hm, masks, cs, cix,
                                           (float*)d_out, (float*)d_out + (size_t)B_Q * KSEL);
}

// Round 11
// 331.118 us; speedup vs baseline: 1.3495x; 1.3495x over previous
//
#include <hip/hip_runtime.h>
#include <hip/hip_bf16.h>
#include <math.h>
#include <float.h>

#define B_Q   1024
#define N_M   50000
#define DIM   256
#define ATOMS 200
#define KSEL  8
#define NCHUNK 40
#define CHUNK  1280       // rows per chunk (16-aligned for fragment groups)
#define MT    128
#define NMT   10          // CHUNK/MT exactly
#define CPC   8           // candidates kept per (query, chunk)
#define NC    (NCHUNK * CPC)   // 320 candidates per query
#define T16   16          // finalize rescore set
#define TROWS 64          // transform rows per block (round-7 best structure)
#define APX   264         // A-plane LDS row stride in bf16 elems (528B, 16B-aligned)

typedef __attribute__((ext_vector_type(8))) short bf16x8;
typedef __attribute__((ext_vector_type(4))) float f32x4;

static __device__ inline unsigned short f2bf(float f) {
  __hip_bfloat16 h = __float2bfloat16(f);   // RNE
  return *reinterpret_cast<unsigned short*>(&h);
}

// RNE 3-way split (one-time W prep): x ~= s1+s2+s3, residual <= 2^-27 |x|
static __device__ inline void split3(float x, unsigned short& s1,
                                     unsigned short& s2, unsigned short& s3) {
  __hip_bfloat16 b1 = __float2bfloat16(x);
  float f1 = __bfloat162float(b1);
  float r1 = x - f1;
  __hip_bfloat16 b2 = __float2bfloat16(r1);
  float f2 = __bfloat162float(b2);
  __hip_bfloat16 b3 = __float2bfloat16(r1 - f2);
  s1 = *reinterpret_cast<unsigned short*>(&b1);
  s2 = *reinterpret_cast<unsigned short*>(&b2);
  s3 = *reinterpret_cast<unsigned short*>(&b3);
}

// Truncation 3-way split (hot path, 2 VALU/tier): residual <= 2^-24 |x|.
static __device__ inline void split3t(float x, unsigned short& s1,
                                      unsigned short& s2, unsigned short& s3) {
  const unsigned u = __float_as_uint(x);
  s1 = (unsigned short)(u >> 16);
  const float f1 = __uint_as_float(u & 0xffff0000u);
  const float r1 = x - f1;                       // exact
  const unsigned v = __float_as_uint(r1);
  s2 = (unsigned short)(v >> 16);
  const float f2 = __uint_as_float(v & 0xffff0000u);
  const float r2 = r1 - f2;                      // exact
  s3 = (unsigned short)(__float_as_uint(r2) >> 16);
}

// fp32 tanh via HW v_exp_f32 (~1ulp): rel err ~1.5e-7.
static __device__ inline float tanh32(float z) {
  float tz = fabsf(z) * 2.885390082f;           // 2|z|*log2(e)
  tz = fminf(tz, 120.f);
  const float E = __builtin_amdgcn_exp2f(tz);   // e^{2|z|}
  const float T = 1.f - 2.f / (E + 1.f);
  return (z >= 0.f) ? T : -T;
}

// ---------------------------------------------------------------------------
// W pre-split: Wt planes in B-FRAGMENT-MAJOR layout (same convention as Hmb):
// for B element (n, k): off = ((n>>4)*8 + (k>>5))*512
//   + ((k>>3)&3)*128 + (n&15)*8 + (k&7).
// Makes transform's Wt loads single coalesced 1KB wave-loads.
// ---------------------------------------------------------------------------
__global__ __launch_bounds__(256) void wsplit_kernel(
    const float* __restrict__ W,
    unsigned short* __restrict__ Wt1, unsigned short* __restrict__ Wt2,
    unsigned short* __restrict__ Wt3)
{
  const int n = blockIdx.x;
  const int k = threadIdx.x;
  unsigned short s1, s2, s3;
  split3(W[(size_t)k * DIM + n], s1, s2, s3);
  const size_t off = ((size_t)(n >> 4) * 8 + (k >> 5)) * 512
                   + (size_t)(((k >> 3) & 3) * 128 + (n & 15) * 8 + (k & 7));
  Wt1[off] = s1;
  Wt2[off] = s2;
  Wt3[off] = s3;
}

// ---------------------------------------------------------------------------
// Transform v10: round-7 structure (measured 109us, session-best total)
// with ONE change — Wt loads are fragment-major (coalesced 1KB wave-loads)
// instead of 16 scattered 512B-strided rows. Round-9 post-mortem: v9's
// barrier-free strips destroyed B-reuse (24KB Wt traffic/row, 177us);
// v8's co-residency was neutral. The untested half of the round-8 theory
// is the scattered Wt pattern — the same fix that took score 154->110us.
// Block = 64 rows x 1024 threads (16 waves); wave w owns output cols
// [16w,16w+16): Wt read ONCE per block (24 coalesced 1KB loads/wave with
// ks+1 double-buffer), A-planes staged in LDS (101KB, truncation splits).
// MFMA layouts: A[m=lane&15][k=quad*8+j], B[n=lane&15][k=quad*8+j],
// D col=lane&15 row=quad*4+reg. Epilogue: tanh, 2-level row-norm reduce,
// scale, aux. Hb FRAGMENT-MAJOR (score reader unchanged).
// ---------------------------------------------------------------------------
__global__ __launch_bounds__(1024) void transform_kernel(
    const float* __restrict__ X, int nrows,
    const unsigned short* __restrict__ Wt1, const unsigned short* __restrict__ Wt2,
    const unsigned short* __restrict__ Wt3, const float* __restrict__ bvec,
    float* __restrict__ H, unsigned short* __restrict__ Hb,
    float2* __restrict__ aux)
{
  __shared__ __align__(16) unsigned short X1s[TROWS * APX];
  __shared__ __align__(16) unsigned short X2s[TROWS * APX];
  __shared__ __align__(16) unsigned short X3s[TROWS * APX];
  __shared__ float red[16][TROWS];
  __shared__ float sArr[TROWS];

  const int t    = threadIdx.x;
  const int lane = t & 63;
  const int wave = t >> 6;
  const int row0 = blockIdx.x * TROWS;

  // stage + split X tile [64][256]: thread owns (row r, 16 cols at c0)
  {
    const int r  = t >> 4;
    const int c0 = (t & 15) * 16;
    int gr = row0 + r; if (gr >= nrows) gr = nrows - 1;   // clamp (stores guarded)
    const float4* src = (const float4*)(X + (size_t)gr * DIM + c0);
    bf16x8 p1[2], p2[2], p3[2];
#pragma unroll
    for (int half = 0; half < 2; ++half) {
#pragma unroll
      for (int v = 0; v < 2; ++v) {
        const float4 x4 = src[half * 2 + v];
        const float xv[4] = {x4.x, x4.y, x4.z, x4.w};
#pragma unroll
        for (int i = 0; i < 4; ++i) {
          unsigned short s1, s2, s3;
          split3t(xv[i], s1, s2, s3);
          p1[half][v * 4 + i] = (short)s1;
          p2[half][v * 4 + i] = (short)s2;
          p3[half][v * 4 + i] = (short)s3;
        }
      }
      *(bf16x8*)(X1s + r * APX + c0 + half * 8) = p1[half];
      *(bf16x8*)(X2s + r * APX + c0 + half * 8) = p2[half];
      *(bf16x8*)(X3s + r * APX + c0 + half * 8) = p3[half];
    }
  }
  __syncthreads();

  const int lx   = lane & 15;    // A row m / B col n / D col
  const int quad = lane >> 4;    // k-group / D row-quad
  const int n0   = wave * 16;    // this wave's output col-tile (g = wave)

  f32x4 acc[4];
#pragma unroll
  for (int ms = 0; ms < 4; ++ms) { acc[ms][0] = 0.f; acc[ms][1] = 0.f; acc[ms][2] = 0.f; acc[ms][3] = 0.f; }

  // FRAG-MAJOR Wt: wave w's (g=w, ks) block = (w*8+ks)*512 + lane*8 — coalesced
  const size_t bbase = (size_t)wave * 4096 + (size_t)lane * 8;
  bf16x8 b1c = *(const bf16x8*)(Wt1 + bbase);
  bf16x8 b2c = *(const bf16x8*)(Wt2 + bbase);
  bf16x8 b3c = *(const bf16x8*)(Wt3 + bbase);

#pragma unroll
  for (int ks = 0; ks < 8; ++ks) {
    bf16x8 b1n, b2n, b3n;
    if (ks < 7) {                       // prefetch next k-step's B
      const size_t nb = bbase + (size_t)(ks + 1) * 512;
      b1n = *(const bf16x8*)(Wt1 + nb);
      b2n = *(const bf16x8*)(Wt2 + nb);
      b3n = *(const bf16x8*)(Wt3 + nb);
    }
    const int ko = ks * 32 + quad * 8;
#pragma unroll
    for (int ms = 0; ms < 4; ++ms) {
      const int ar = (ms * 16 + lx) * APX + ko;
      const bf16x8 a1 = *(const bf16x8*)(X1s + ar);
      const bf16x8 a2 = *(const bf16x8*)(X2s + ar);
      const bf16x8 a3 = *(const bf16x8*)(X3s + ar);
      acc[ms] = __builtin_amdgcn_mfma_f32_16x16x32_bf16(a1, b1c, acc[ms], 0, 0, 0);
      acc[ms] = __builtin_amdgcn_mfma_f32_16x16x32_bf16(a1, b2c, acc[ms], 0, 0, 0);
      acc[ms] = __builtin_amdgcn_mfma_f32_16x16x32_bf16(a2, b1c, acc[ms], 0, 0, 0);
      acc[ms] = __builtin_amdgcn_mfma_f32_16x16x32_bf16(a1, b3c, acc[ms], 0, 0, 0);
      acc[ms] = __builtin_amdgcn_mfma_f32_16x16x32_bf16(a2, b2c, acc[ms], 0, 0, 0);
      acc[ms] = __builtin_amdgcn_mfma_f32_16x16x32_bf16(a3, b1c, acc[ms], 0, 0, 0);
    }
    b1c = b1n; b2c = b2n; b3c = b3n;
  }

  // bias + tanh: lane holds rows ms*16+quad*4+r, col n0+lx (bias col-constant)
  const float bb = bvec[n0 + lx];
  float h[4][4];
#pragma unroll
  for (int ms = 0; ms < 4; ++ms)
#pragma unroll
    for (int r = 0; r < 4; ++r)
      h[ms][r] = tanh32(acc[ms][r] + bb);

  // row-norm partial over this wave's 16 cols (shuffle over lx)
  float p[4][4];
#pragma unroll
  for (int ms = 0; ms < 4; ++ms)
#pragma unroll
    for (int r = 0; r < 4; ++r) p[ms][r] = h[ms][r] * h[ms][r];
#pragma unroll
  for (int off = 1; off < 16; off <<= 1)
#pragma unroll
    for (int ms = 0; ms < 4; ++ms)
#pragma unroll
      for (int r = 0; r < 4; ++r) p[ms][r] += __shfl_xor(p[ms][r], off);
  if (lx == 0)
#pragma unroll
    for (int ms = 0; ms < 4; ++ms)
#pragma unroll
      for (int r = 0; r < 4; ++r) red[wave][ms * 16 + quad * 4 + r] = p[ms][r];
  __syncthreads();

  if (t < TROWS) {
    float nsq = 0.f;
#pragma unroll
    for (int w = 0; w < 16; ++w) nsq += red[w][t];
    const float nrm = sqrtf(nsq);
    sArr[t] = (nrm > 0.95f) ? (0.95f / nrm) : 1.f;
  }
  __syncthreads();

  float u[4][4];
#pragma unroll
  for (int ms = 0; ms < 4; ++ms)
#pragma unroll
    for (int r = 0; r < 4; ++r) {
      const float sc = sArr[ms * 16 + quad * 4 + r];
      u[ms][r] = h[ms][r] * sc;
      p[ms][r] = u[ms][r] * u[ms][r];
    }
#pragma unroll
  for (int off = 1; off < 16; off <<= 1)
#pragma unroll
    for (int ms = 0; ms < 4; ++ms)
#pragma unroll
      for (int r = 0; r < 4; ++r) p[ms][r] += __shfl_xor(p[ms][r], off);
  if (lx == 0)
#pragma unroll
    for (int ms = 0; ms < 4; ++ms)
#pragma unroll
      for (int r = 0; r < 4; ++r) red[wave][ms * 16 + quad * 4 + r] = p[ms][r];

  // stores: H fp32 (row-major) + Hb bf16 (FRAGMENT-MAJOR, guarded rows)
  const int colv = n0 + lx;
  const int ksb  = colv >> 5;                         // fragment k-slot
  const int qoff = ((colv >> 3) & 3) * 128 + (colv & 7);  // quad*16 lanes *8 + j
#pragma unroll
  for (int ms = 0; ms < 4; ++ms)
#pragma unroll
    for (int r = 0; r < 4; ++r) {
      const int grow = row0 + ms * 16 + quad * 4 + r;
      if (grow < nrows) {
        H[(size_t)grow * DIM + colv] = u[ms][r];
        Hb[((size_t)((row0 >> 4) + ms) * 8 + ksb) * 512 + qoff + (quad * 4 + r) * 8]
            = f2bf(u[ms][r]);
      }
    }
  __syncthreads();
  if (t < TROWS) {
    const int grow = row0 + t;
    if (grow < nrows) {
      float ysq = 0.f;
#pragma unroll
      for (int w = 0; w < 16; ++w) ysq += red[w][t];
      aux[grow] = make_float2(ysq, 1.f / (1.f - ysq));
    }
  }
}

// ---------------------------------------------------------------------------
// Score (MFMA), v7 (unchanged): coalesced frag-major pipeline + u32 packed
// keys + 5-op min/max sorted insert. See round-6/7 notes: coalescing took
// 154->110us; u32 keys cut the VALU insert cost (score now <108us).
// key = (fp32 score bits & ~31) | (mt*2+ms); decode at extraction:
// gi = mbase + wave*32 + lx + mt*128 + ms*16. fp64 rescore fixes order.
// ---------------------------------------------------------------------------
__global__ __launch_bounds__(256) void score_kernel(
    const unsigned short* __restrict__ Hqb, const unsigned short* __restrict__ Hmb,
    const float2* __restrict__ auxq, const float2* __restrict__ auxm,
    float* __restrict__ cand_s, int* __restrict__ cand_i)
{
  __shared__ __align__(16) unsigned short Afs[16 * 64 * 8]; // 16 KB, frag-order
  __shared__ unsigned long long wtop[4][32][CPC];           // 8 KB

  const int t    = threadIdx.x;
  const int lane = t & 63;
  const int wave = t >> 6;
  const int q0   = blockIdx.y * 32;
  const int c    = blockIdx.x;
  const int mbase = c * CHUNK;
  const int lx   = lane & 15;
  const int quad = lane >> 4;

  // stage A fragments into LDS (slot = ks*2+qs; frag-major source, coalesced)
#pragma unroll
  for (int i = 0; i < 4; ++i) {
    const int sl = wave * 4 + i;
    const int ks = sl >> 1, qs = sl & 1;
    const bf16x8 a = *(const bf16x8*)(Hqb + ((size_t)((q0 >> 4) + qs) * 8 + ks) * 512 + (size_t)lane * 8);
    *(bf16x8*)(Afs + ((size_t)sl * 64 + lane) * 8) = a;
  }
  // per-row query norms (row = qs*4+r; rows 0-3 -> qs=0, rows 4-7 -> qs=1)
  const float xq0 = auxq[q0 +      quad * 4 + 0].x;
  const float xq1 = auxq[q0 +      quad * 4 + 1].x;
  const float xq2 = auxq[q0 +      quad * 4 + 2].x;
  const float xq3 = auxq[q0 +      quad * 4 + 3].x;
  const float xq4 = auxq[q0 + 16 + quad * 4 + 0].x;
  const float xq5 = auxq[q0 + 16 + quad * 4 + 1].x;
  const float xq6 = auxq[q0 + 16 + quad * 4 + 2].x;
  const float xq7 = auxq[q0 + 16 + quad * 4 + 3].x;
  __syncthreads();          // the ONLY pre-merge barrier

  // 24 named packed u32 top-3 keys (sorted ascending: a <= b <= c)
  unsigned t0a=0xFFFFFFFFu,t0b=0xFFFFFFFFu,t0c=0xFFFFFFFFu;
  unsigned t1a=0xFFFFFFFFu,t1b=0xFFFFFFFFu,t1c=0xFFFFFFFFu;
  unsigned t2a=0xFFFFFFFFu,t2b=0xFFFFFFFFu,t2c=0xFFFFFFFFu;
  unsigned t3a=0xFFFFFFFFu,t3b=0xFFFFFFFFu,t3c=0xFFFFFFFFu;
  unsigned t4a=0xFFFFFFFFu,t4b=0xFFFFFFFFu,t4c=0xFFFFFFFFu;
  unsigned t5a=0xFFFFFFFFu,t5b=0xFFFFFFFFu,t5c=0xFFFFFFFFu;
  unsigned t6a=0xFFFFFFFFu,t6b=0xFFFFFFFFu,t6c=0xFFFFFFFFu;
  unsigned t7a=0xFFFFFFFFu,t7b=0xFFFFFFFFu,t7c=0xFFFFFFFFu;

  const int colw = wave * 32 + lx;       // within-128-tile column, ms=0

  // fragment-major B pointer: wave's group pair g0 = (mbase>>4) + wave*2
  // frag (g, ks) block = 512 elems; group stride = 8*512 = 4096 elems.
  const unsigned short* Bp = Hmb + (size_t)((mbase >> 4) + wave * 2) * 4096 + (size_t)lane * 8;
#define LD(OFS) (*(const bf16x8*)(Bp + (OFS)))

// one MFMA k-step: A slots (KS*2+0 / KS*2+1) x named B frags
#define KSTEP(KS, BA, BB) do {                                                        \
    const bf16x8 a0_ = *(const bf16x8*)(Afs + (((KS) * 2 + 0) * 64 + lane) * 8);      \
    const bf16x8 a1_ = *(const bf16x8*)(Afs + (((KS) * 2 + 1) * 64 + lane) * 8);      \
    acc00 = __builtin_amdgcn_mfma_f32_16x16x32_bf16(a0_, BA, acc00, 0, 0, 0);         \
    acc01 = __builtin_amdgcn_mfma_f32_16x16x32_bf16(a0_, BB, acc01, 0, 0, 0);         \
    acc10 = __builtin_amdgcn_mfma_f32_16x16x32_bf16(a1_, BA, acc10, 0, 0, 0);         \
    acc11 = __builtin_amdgcn_mfma_f32_16x16x32_bf16(a1_, BB, acc11, 0, 0, 0);         \
  } while (0)

// u32-key score + 5-op sorted-insert (keep 3 smallest), unconditional
#define SCOREU(ACC, R, YM, RO, CODE, XQ, T0, T1, T2) do {                             \
    const float sv_ = fmaxf(fmaf(-2.f, (ACC)[R], (XQ) + (YM)), 0.f) * (RO);           \
    const unsigned k_ = (__float_as_uint(sv_) & 0xFFFFFFE0u) | (unsigned)(CODE);      \
    const unsigned a_ = min(T0, k_);                                                  \
    const unsigned x_ = max(T0, k_);                                                  \
    const unsigned b_ = min(T1, x_);                                                  \
    const unsigned y_ = max(T1, x_);                                                  \
    const unsigned c_ = min(T2, y_);                                                  \
    T0 = a_; T1 = b_; T2 = c_;                                                        \
  } while (0)

// masked variant (tail chunk only): invalid -> 0xFFFFFFFF sentinel
#define SCOREM(ACC, R, YM, RO, OK, CODE, XQ, T0, T1, T2) do {                         \
    const float sv_ = fmaxf(fmaf(-2.f, (ACC)[R], (XQ) + (YM)), 0.f) * (RO);           \
    const unsigned kr_ = (__float_as_uint(sv_) & 0xFFFFFFE0u) | (unsigned)(CODE);     \
    const unsigned k_ = (OK) ? kr_ : 0xFFFFFFFFu;                                     \
    const unsigned a_ = min(T0, k_);                                                  \
    const unsigned x_ = max(T0, k_);                                                  \
    const unsigned b_ = min(T1, x_);                                                  \
    const unsigned y_ = max(T1, x_);                                                  \
    const unsigned c_ = min(T2, y_);                                                  \
    T0 = a_; T1 = b_; T2 = c_;                                                        \
  } while (0)

#define SCORE16U(C0, C1) do {                                                         \
    const float ym0 = aux0.x, ro0 = aux0.y;                                           \
    const float ym1 = aux1.x, ro1 = aux1.y;                                           \
    SCOREU(acc00, 0, ym0, ro0, C0, xq0, t0a, t0b, t0c);                               \
    SCOREU(acc00, 1, ym0, ro0, C0, xq1, t1a, t1b, t1c);                               \
    SCOREU(acc00, 2, ym0, ro0, C0, xq2, t2a, t2b, t2c);                               \
    SCOREU(acc00, 3, ym0, ro0, C0, xq3, t3a, t3b, t3c);                               \
    SCOREU(acc01, 0, ym1, ro1, C1, xq0, t0a, t0b, t0c);                               \
    SCOREU(acc01, 1, ym1, ro1, C1, xq1, t1a, t1b, t1c);                               \
    SCOREU(acc01, 2, ym1, ro1, C1, xq2, t2a, t2b, t2c);                               \
    SCOREU(acc01, 3, ym1, ro1, C1, xq3, t3a, t3b, t3c);                               \
    SCOREU(acc10, 0, ym0, ro0, C0, xq4, t4a, t4b, t4c);                               \
    SCOREU(acc10, 1, ym0, ro0, C0, xq5, t5a, t5b, t5c);                               \
    SCOREU(acc10, 2, ym0, ro0, C0, xq6, t6a, t6b, t6c);                               \
    SCOREU(acc10, 3, ym0, ro0, C0, xq7, t7a, t7b, t7c);                               \
    SCOREU(acc11, 0, ym1, ro1, C1, xq4, t4a, t4b, t4c);                               \
    SCOREU(acc11, 1, ym1, ro1, C1, xq5, t5a, t5b, t5c);                               \
    SCOREU(acc11, 2, ym1, ro1, C1, xq6, t6a, t6b, t6c);                               \
    SCOREU(acc11, 3, ym1, ro1, C1, xq7, t7a, t7b, t7c);                               \
  } while (0)

#define SCORE16M(OK0, OK1, C0, C1) do {                                               \
    const float ym0 = aux0.x, ro0 = aux0.y;                                           \
    const float ym1 = aux1.x, ro1 = aux1.y;                                           \
    SCOREM(acc00, 0, ym0, ro0, OK0, C0, xq0, t0a, t0b, t0c);                          \
    SCOREM(acc00, 1, ym0, ro0, OK0, C0, xq1, t1a, t1b, t1c);                          \
    SCOREM(acc00, 2, ym0, ro0, OK0, C0, xq2, t2a, t2b, t2c);                          \
    SCOREM(acc00, 3, ym0, ro0, OK0, C0, xq3, t3a, t3b, t3c);                          \
    SCOREM(acc01, 0, ym1, ro1, OK1, C1, xq0, t0a, t0b, t0c);                          \
    SCOREM(acc01, 1, ym1, ro1, OK1, C1, xq1, t1a, t1b, t1c);                          \
    SCOREM(acc01, 2, ym1, ro1, OK1, C1, xq2, t2a, t2b, t2c);                          \
    SCOREM(acc01, 3, ym1, ro1, OK1, C1, xq3, t3a, t3b, t3c);                          \
    SCOREM(acc10, 0, ym0, ro0, OK0, C0, xq4, t4a, t4b, t4c);                          \
    SCOREM(acc10, 1, ym0, ro0, OK0, C0, xq5, t5a, t5b, t5c);                          \
    SCOREM(acc10, 2, ym0, ro0, OK0, C0, xq6, t6a, t6b, t6c);                          \
    SCOREM(acc10, 3, ym0, ro0, OK0, C0, xq7, t7a, t7b, t7c);                          \
    SCOREM(acc11, 0, ym1, ro1, OK1, C1, xq4, t4a, t4b, t4c);                          \
    SCOREM(acc11, 1, ym1, ro1, OK1, C1, xq5, t5a, t5b, t5c);                          \
    SCOREM(acc11, 2, ym1, ro1, OK1, C1, xq6, t6a, t6b, t6c);                          \
    SCOREM(acc11, 3, ym1, ro1, OK1, C1, xq7, t7a, t7b, t7c);                          \
  } while (0)

  if (c != NCHUNK - 1) {
    // ---- chunks 0..38: 10 full unmasked mtiles, half-tile pipeline ----
    int midx = mbase + colw;   // only for aux addressing
    // preload X = k-half0 of mtile 0 (ks0..3 of both 16-row groups)
    bf16x8 xA0 = LD(0),    xA1 = LD(512),  xA2 = LD(1024), xA3 = LD(1536);
    bf16x8 xB0 = LD(4096), xB1 = LD(4608), xB2 = LD(5120), xB3 = LD(5632);

    for (int mt = 0; mt < NMT - 1; ++mt) {   // mt 0..8: branch-free body
      // issue Y = k-half1 of current mtile
      bf16x8 yA0 = LD(2048), yA1 = LD(2560), yA2 = LD(3072), yA3 = LD(3584);
      bf16x8 yB0 = LD(6144), yB1 = LD(6656), yB2 = LD(7168), yB3 = LD(7680);
      const float2 aux0 = auxm[midx];
      const float2 aux1 = auxm[midx + 16];

      f32x4 acc00 = {0.f, 0.f, 0.f, 0.f};
      f32x4 acc01 = {0.f, 0.f, 0.f, 0.f};
      f32x4 acc10 = {0.f, 0.f, 0.f, 0.f};
      f32x4 acc11 = {0.f, 0.f, 0.f, 0.f};

      KSTEP(0, xA0, xB0);
      KSTEP(1, xA1, xB1);
      KSTEP(2, xA2, xB2);
      KSTEP(3, xA3, xB3);

      // advance, issue X of NEXT mtile (in flight across inserts)
      Bp += 8 * 4096;
      xA0 = LD(0);    xA1 = LD(512);  xA2 = LD(1024); xA3 = LD(1536);
      xB0 = LD(4096); xB1 = LD(4608); xB2 = LD(5120); xB3 = LD(5632);

      KSTEP(4, yA0, yB0);
      KSTEP(5, yA1, yB1);
      KSTEP(6, yA2, yB2);
      KSTEP(7, yA3, yB3);

      SCORE16U(mt * 2, mt * 2 + 1);
      midx += MT;
    }

    { // final mtile mt=9 (X preloaded, no further prefetch), unmasked
      bf16x8 yA0 = LD(2048), yA1 = LD(2560), yA2 = LD(3072), yA3 = LD(3584);
      bf16x8 yB0 = LD(6144), yB1 = LD(6656), yB2 = LD(7168), yB3 = LD(7680);
      const float2 aux0 = auxm[midx];
      const float2 aux1 = auxm[midx + 16];

      f32x4 acc00 = {0.f, 0.f, 0.f, 0.f};
      f32x4 acc01 = {0.f, 0.f, 0.f, 0.f};
      f32x4 acc10 = {0.f, 0.f, 0.f, 0.f};
      f32x4 acc11 = {0.f, 0.f, 0.f, 0.f};

      KSTEP(0, xA0, xB0);
      KSTEP(1, xA1, xB1);
      KSTEP(2, xA2, xB2);
      KSTEP(3, xA3, xB3);
      KSTEP(4, yA0, yB0);
      KSTEP(5, yA1, yB1);
      KSTEP(6, yA2, yB2);
      KSTEP(7, yA3, yB3);

      SCORE16U((NMT - 1) * 2, (NMT - 1) * 2 + 1);
    }
  } else {
    // ---- tail chunk 39: rows 49920..49999 valid (80) -> 1 masked mtile ----
    // Reads stay within the padded 50048-row fragment region; junk cols
    // (incl. possible NaN) cndmask'd to sentinel BEFORE insert.
    const int vrem = N_M - mbase;               // 80
    const bool ok0 = colw < vrem;
    const bool ok1 = colw + 16 < vrem;
    const int midx = mbase + colw;

    bf16x8 xA0 = LD(0),    xA1 = LD(512),  xA2 = LD(1024), xA3 = LD(1536);
    bf16x8 xB0 = LD(4096), xB1 = LD(4608), xB2 = LD(5120), xB3 = LD(5632);
    bf16x8 yA0 = LD(2048), yA1 = LD(2560), yA2 = LD(3072), yA3 = LD(3584);
    bf16x8 yB0 = LD(6144), yB1 = LD(6656), yB2 = LD(7168), yB3 = LD(7680);
    const float2 aux0 = auxm[midx];
    const float2 aux1 = auxm[midx + 16];

    f32x4 acc00 = {0.f, 0.f, 0.f, 0.f};
    f32x4 acc01 = {0.f, 0.f, 0.f, 0.f};
    f32x4 acc10 = {0.f, 0.f, 0.f, 0.f};
    f32x4 acc11 = {0.f, 0.f, 0.f, 0.f};

    KSTEP(0, xA0, xB0);
    KSTEP(1, xA1, xB1);
    KSTEP(2, xA2, xB2);
    KSTEP(3, xA3, xB3);
    KSTEP(4, yA0, yB0);
    KSTEP(5, yA1, yB1);
    KSTEP(6, yA2, yB2);
    KSTEP(7, yA3, yB3);

    SCORE16M(ok0, ok1, 0, 1);
  }

#undef LD
#undef KSTEP
#undef SCOREU
#undef SCOREM
#undef SCORE16U
#undef SCORE16M

  // key -> u64 (key<<32 | global index): restores unique keys for the
  // equality-pop merge. decode: mt=(k>>1)&15, ms=k&1.
#define K2E(K) ( (((unsigned long long)(K)) << 32) |                                  \
    (unsigned)(mbase + wave * 32 + lx + (((K) & 30u) >> 1) * 128 + ((K) & 1u) * 16) )

  // per-wave extraction: per query-row, 16 lanes x top-3 -> wave top-8.
  // (quads handle 4 query-rows in parallel; shfl offsets 1..8 stay in-quad)
#define EXTRACT_ROW(WIDX, T0, T1, T2) do {                                            \
    unsigned long long p0 = K2E(T0), p1 = K2E(T1), p2 = K2E(T2);                      \
    for (int rd = 0; rd < CPC; ++rd) {                                                \
      unsigned long long lm = (p0 < p1) ? p0 : p1;                                    \
      lm = (p2 < lm) ? p2 : lm;                                                       \
      unsigned long long gm = lm;                                                     \
      for (int off = 1; off < 16; off <<= 1) {                                        \
        const unsigned long long o = __shfl_xor(gm, off);                             \
        gm = (o < gm) ? o : gm;                                                       \
      }                                                                               \
      if      (p0 == gm) p0 = ~0ULL;                                                  \
      else if (p1 == gm) p1 = ~0ULL;                                                  \
      else if (p2 == gm) p2 = ~0ULL;                                                  \
      if (lx == 0) wtop[wave][WIDX][rd] = gm;                                         \
    }                                                                                 \
  } while (0)

  EXTRACT_ROW(quad * 4 + 0,      t0a, t0b, t0c);
  EXTRACT_ROW(quad * 4 + 1,      t1a, t1b, t1c);
  EXTRACT_ROW(quad * 4 + 2,      t2a, t2b, t2c);
  EXTRACT_ROW(quad * 4 + 3,      t3a, t3b, t3c);
  EXTRACT_ROW(16 + quad * 4 + 0, t4a, t4b, t4c);
  EXTRACT_ROW(16 + quad * 4 + 1, t5a, t5b, t5c);
  EXTRACT_ROW(16 + quad * 4 + 2, t6a, t6b, t6c);
  EXTRACT_ROW(16 + quad * 4 + 3, t7a, t7b, t7c);
#undef EXTRACT_ROW
#undef K2E
  __syncthreads();

  // cross-wave merge: 8 threads per query, 4 waves x 8 -> top-8 -> cand
  {
    const int qr = t >> 3;        // 0..31
    const int sp = t & 7;
    unsigned long long v0 = wtop[0][qr][sp];
    unsigned long long v1 = wtop[1][qr][sp];
    unsigned long long v2 = wtop[2][qr][sp];
    unsigned long long v3 = wtop[3][qr][sp];
    const size_t cbase = ((size_t)(q0 + qr) * NCHUNK + c) * CPC;
    for (int rd = 0; rd < CPC; ++rd) {
      unsigned long long lm = (v0 < v1) ? v0 : v1;
      const unsigned long long l2 = (v2 < v3) ? v2 : v3;
      lm = (l2 < lm) ? l2 : lm;
      unsigned long long gm = lm;
#pragma unroll
      for (int off = 1; off < 8; off <<= 1) {
        const unsigned long long o = __shfl_xor(gm, off);
        gm = (o < gm) ? o : gm;
      }
      if      (v0 == gm) v0 = ~0ULL;
      else if (v1 == gm) v1 = ~0ULL;
      else if (v2 == gm) v2 = ~0ULL;
      else if (v3 == gm) v3 = ~0ULL;
      if (sp == 0) {
        cand_s[cbase + rd] = __uint_as_float((unsigned int)(gm >> 32));
        cand_i[cbase + rd] = (int)(unsigned int)(gm & 0xffffffffu);
      }
    }
  }
}

// ---------------------------------------------------------------------------
// Finalize: per query, 256 threads (4 waves): parallel candidate merge
// 320 -> 4x16 -> top-16 (fp32 score, idx tie-break), fp64 rescore (4 cands
// per wave) -> exact top-8 order, softmax, parallel mask gather.
// ---------------------------------------------------------------------------
__global__ __launch_bounds__(256) void finalize_kernel(
    const float* __restrict__ Hq, const float* __restrict__ Hm,
    const float* __restrict__ masks,
    const float* __restrict__ cand_s, const int* __restrict__ cand_i,
    float* __restrict__ outW, float* __restrict__ outH)
{
  const int q    = blockIdx.x;
  const int t    = threadIdx.x;
  const int lane = t & 63;
  const int wave = t >> 6;

  __shared__ unsigned long long wtop[4][T16];
  __shared__ int    selIdx[T16];
  __shared__ double dArr[T16];
  __shared__ int    fin_i[KSEL];
  __shared__ double fin_d[KSEL];
  __shared__ double ew[KSEL];

  // phase 1: each wave takes 80 candidates -> its top-16 (indices unique)
  {
    const size_t base = (size_t)q * NC + (size_t)wave * (NC / 4);
    unsigned long long pk[2];
#pragma unroll
    for (int s = 0; s < 2; ++s) {
      const int c = lane + 64 * s;
      pk[s] = (c < NC / 4)
        ? ((((unsigned long long)__float_as_uint(cand_s[base + c])) << 32) | (unsigned int)cand_i[base + c])
        : ~0ULL;
    }
    for (int r = 0; r < T16; ++r) {
      unsigned long long lm = (pk[0] < pk[1]) ? pk[0] : pk[1];
      unsigned long long gm = lm;
#pragma unroll
      for (int off = 1; off < 64; off <<= 1) {
        unsigned long long o = __shfl_xor(gm, off);
        gm = (o < gm) ? o : gm;
      }
      bool done = false;
#pragma unroll
      for (int s = 0; s < 2; ++s) if (!done && pk[s] == gm) { pk[s] = ~0ULL; done = true; }
      if (lane == 0) wtop[wave][r] = gm;
    }
  }
  __syncthreads();

  // phase 2: wave 0 merges 64 -> global top-16
  if (wave == 0) {
    unsigned long long v = wtop[lane >> 4][lane & 15];
    for (int r = 0; r < T16; ++r) {
      unsigned long long gm = v;
#pragma unroll
      for (int off = 1; off < 64; off <<= 1) {
        unsigned long long o = __shfl_xor(gm, off);
        gm = (o < gm) ? o : gm;
      }
      if (v == gm) v = ~0ULL;
      if (lane == 0) selIdx[r] = (int)(unsigned int)(gm & 0xffffffffULL);
    }
  }
  __syncthreads();

  // phase 3: fp64 rescore, 4 candidates per wave
  const float4 q4 = *(const float4*)(Hq + (size_t)q * DIM + 4 * lane);
  double xp_ = (double)q4.x * q4.x + (double)q4.y * q4.y + (double)q4.z * q4.z + (double)q4.w * q4.w;
#pragma unroll
  for (int off = 1; off < 64; off <<= 1) xp_ += __shfl_xor(xp_, off);
  const double xsq = xp_;

  for (int r = wave; r < T16; r += 4) {
    const int cidx = selIdx[r];
    const float4 m4 = *(const float4*)(Hm + (size_t)cidx * DIM + 4 * lane);
    double dp = (double)q4.x * m4.x + (double)q4.y * m4.y + (double)q4.z * m4.z + (double)q4.w * m4.w;
    double yp = (double)m4.x * m4.x + (double)m4.y * m4.y + (double)m4.z * m4.z + (double)m4.w * m4.w;
#pragma unroll
    for (int off = 1; off < 64; off <<= 1) { dp += __shfl_xor(dp, off); yp += __shfl_xor(yp, off); }
    if (lane == 0) {
      double diff = xsq + yp - 2.0 * dp; if (diff < 0.0) diff = 0.0;
      double den = (1.0 - xsq) * (1.0 - yp);
      double arg = 1.0 + 2.0 * diff / (den + 1e-8);
      const double lo = 1.0 + 1e-6;
      if (arg < lo) arg = lo;
      dArr[r] = log(arg + sqrt(arg * arg - 1.0));   // arccosh
    }
  }
  __syncthreads();

  // phase 4: exact rank (dist, idx) -> top-8, softmax
  if (t < T16) {
    const double dj = dArr[t]; const int ij = selIdx[t];
    int rank = 0;
#pragma unroll
    for (int i = 0; i < T16; ++i)
      rank += (dArr[i] < dj || (dArr[i] == dj && selIdx[i] < ij)) ? 1 : 0;
    if (rank < KSEL) { fin_d[rank] = dj; fin_i[rank] = ij; }
  }
  __syncthreads();
  if (t < KSEL) ew[t] = exp(fin_d[0] - fin_d[t]);
  __syncthreads();
  if (t < KSEL) {
    double ssum = 0.0;
#pragma unroll
    for (int i = 0; i < KSEL; ++i) ssum += ew[i];
    outW[(size_t)q * KSEL + t] = (float)(ew[t] / ssum);
  }

  // phase 5: mask gather, 32 threads per output row
  const int g  = t >> 5;
  const int l0 = t & 31;
  const int row = fin_i[g];
  for (int l = l0; l < ATOMS; l += 32)
    outH[((size_t)q * KSEL + g) * ATOMS + l] = masks[(size_t)row * ATOMS + l];
}

// ---------------------------------------------------------------------------
extern "C" void kernel_launch(void* const* d_in, const int* in_sizes, int n_in,
                              void* d_out, int out_size, void* d_ws, size_t ws_size,
                              hipStream_t stream) {
  const float* Q     = (const float*)d_in[0];   // [1024,256]
  const float* M     = (const float*)d_in[1];   // [50000,256]
  const float* masks = (const float*)d_in[2];   // [50000,200]
  const float* W     = (const float*)d_in[3];   // [256,256]
  const float* bv    = (const float*)d_in[4];   // [256]
  // d_in[5] = k (always 8, hard-coded)

  char* w = (char*)d_ws;
  float*          Hq   = (float*)(w);                       //  1,048,576 B
  float*          Hm   = (float*)(w + 1048576);             // 51,200,000 B
  unsigned short* Hqb  = (unsigned short*)(w + 52248576);   //    524,288 B (frag-major, 64 groups)
  unsigned short* Hmb  = (unsigned short*)(w + 52772864);   // 25,624,576 B (frag-major, 3128 groups = 50048 rows)
  float2*         auxq = (float2*)(w + 78397440);           //      8,192 B
  float2*         auxm = (float2*)(w + 78405632);           //    400,384 B (padded to 50048)
  float*          cs   = (float*)(w + 78806016);            //  1,310,720 B
  int*            cix  = (int*)(w + 80116736);              //  1,310,720 B -> 81,427,456 total

  // Wt bf16 planes alias the cand_s region (dead until score_kernel writes it)
  unsigned short* Wt1 = (unsigned short*)(w + 78806016);    // 3 x 131,072 B (frag-major)
  unsigned short* Wt2 = Wt1 + DIM * DIM;
  unsigned short* Wt3 = Wt2 + DIM * DIM;

  wsplit_kernel<<<DIM, DIM, 0, stream>>>(W, Wt1, Wt2, Wt3);
  transform_kernel<<<(B_Q + TROWS - 1) / TROWS, 1024, 0, stream>>>(Q, B_Q, Wt1, Wt2, Wt3, bv, Hq, Hqb, auxq);
  transform_kernel<<<(N_M + TROWS - 1) / TROWS, 1024, 0, stream>>>(M, N_M, Wt1, Wt2, Wt3, bv, Hm, Hmb, auxm);
  score_kernel<<<dim3(NCHUNK, B_Q / 32), 256, 0, stream>>>(Hqb, Hmb, auxq, auxm, cs, cix);
  finalize_kernel<<<B_Q, 256, 0, stream>>>(Hq, Hm, masks, cs, cix,
                                           (float*)d_out, (float*)d_out + (size_t)B_Q * KSEL);
}